// Round 7
// baseline (79.308 us; speedup 1.0000x reference)
//
#include <hip/hip_runtime.h>
#include <hip/hip_bf16.h>

typedef __attribute__((ext_vector_type(8))) short bf16x8;
typedef __attribute__((ext_vector_type(4))) float f32x4;
typedef unsigned int u32;
typedef unsigned short u16;

#define NPOS 147456
#define NTILES 9216
#define NBLK 768           // 12 iters/block; 4 blocks/CU (34 KB LDS)
#define ITERS 12           // NTILES / NBLK (exact)

__device__ inline u16 bfc(float f) {
  union { __hip_bfloat16 h; u16 s; } u;
  u.h = __float2bfloat16(f);
  return u.s;
}

// ---------------------------------------------------------------------------
// Prologue: bake bf16 weight fragments into ws (unchanged from R3-R6).
// frag = 512 u16; frag elem (lane,e): A[row=lane&15][k=(lane>>4)*8+e].
// ---------------------------------------------------------------------------
__global__ void prep_kernel(const float* __restrict__ wq, const float* __restrict__ wk,
                            const float* __restrict__ wv, const float* __restrict__ wo,
                            u16* __restrict__ wsf) {
  int gid = blockIdx.x * 256 + threadIdx.x;   // [0, 24576)
  int idx, which;
  if (gid < 8192)       { idx = gid;         which = 0; }
  else if (gid < 12288) { idx = gid - 8192;  which = 1; }
  else if (gid < 16384) { idx = gid - 12288; which = 2; }
  else                  { idx = gid - 16384; which = 3; }
  int fragid = idx >> 9, lane = (idx >> 3) & 63, e = idx & 7;
  int l15 = lane & 15, g = lane >> 4;
  float v;
  if (which == 0) {        // wq: [4][128][16]
    int n = fragid >> 2, kc = fragid & 3;
    int c = kc * 32 + g * 8 + e;
    v = wq[n * 2048 + c * 16 + l15] * 0.25f;   // fold D^-0.5
  } else if (which == 1) { // wk: [4][64][16]
    int n = fragid >> 1, kc = fragid & 1;
    int c = kc * 32 + g * 8 + e;
    v = wk[n * 1024 + c * 16 + l15];
  } else if (which == 2) { // wv
    int n = fragid >> 1, kc = fragid & 1;
    int c = kc * 32 + g * 8 + e;
    v = wv[n * 1024 + c * 16 + l15];
  } else {                 // wo: [4][16][128]
    int n8 = fragid >> 1, kc = fragid & 1;
    int hd = kc * 32 + g * 8 + e;
    v = wo[(hd >> 4) * 2048 + (hd & 15) * 128 + n8 * 16 + l15];
  }
  wsf[gid] = bfc(v);
}

#define WQF(n, kc)  ((((n) * 4 + (kc))) * 64)
#define WKF(n, kc)  ((16 + (n) * 2 + (kc)) * 64)
#define WVF(n, kc)  ((24 + (n) * 2 + (kc)) * 64)
#define WOF(n8, kc) ((32 + (n8) * 2 + (kc)) * 64)

typedef const __attribute__((address_space(1))) u32 gas_u32;
typedef __attribute__((address_space(3))) u32 las_u32;

#define STR2_(x) #x
#define WAITVM(n) asm volatile("s_waitcnt vmcnt(" STR2_(n) ")" ::: "memory")

// ---------------------------------------------------------------------------
// Main: 768 blocks x 4 waves, wave h = head h. tpr DMA'd to 2x16KB LDS
// double-buffer (global_load_lds); q prefetched straight into registers;
// counted vmcnt (4 first body, 14 steady) + raw barriers; WV exchanged
// via 2KB LDS for GEMM4.
// ---------------------------------------------------------------------------
__global__ __launch_bounds__(256, 2) void tpa_kernel(
    const float* __restrict__ qe, const float* __restrict__ tpr,
    const float* __restrict__ tmk_p, const float* __restrict__ ob,
    const u16* __restrict__ wsf, float* __restrict__ out)
{
  __shared__ int4 inbuf4[2][1024];   // 2 x 16 KB tpr tile, XOR-swizzled rows
  __shared__ u32 wvsh32[512];        // 2 KB WV exchange [pos][hd] bf16, swizzled
  char* const inb0 = (char*)inbuf4[0];
  char* const inb1 = (char*)inbuf4[1];
  char* const wvsh = (char*)wvsh32;

  const int tid = threadIdx.x;
  const int wid = tid >> 6;           // wave id = head h
  const int lane = tid & 63;
  const int l15 = lane & 15, g = lane >> 4;
  const int swz = (l15 & 7) << 4;
  const int h = wid;

  // ---- per-lane DMA source bases (inverse-swizzled global addresses) ----
  // chunk m = (wid*4+j)*64 + lane in [0,1024): t=m>>8, pos=(m>>4)&15, c16=m&15
  const char* dmab[4];
  #pragma unroll
  for (int j = 0; j < 4; ++j) {
    int m = (wid * 4 + j) * 64 + lane;
    int t = m >> 8, pos = (m >> 4) & 15, c16 = m & 15;
    int inner = (c16 * 16) ^ ((pos & 7) << 4);
    dmab[j] = (const char*)tpr + ((size_t)t * NPOS + pos) * 256 + inner;
  }

#define STAGE(DST, P)                                                          \
  { _Pragma("unroll") for (int j = 0; j < 4; ++j) {                            \
      const char* s_ = dmab[j] + (size_t)(P) * 256;                            \
      char* d_ = (DST) + (wid * 4 + j) * 1024;                                 \
      __builtin_amdgcn_global_load_lds((gas_u32*)s_, (las_u32*)d_, 16, 0, 0); } }

#define LOADQ(P)                                                               \
  { const f32x4* qb = reinterpret_cast<const f32x4*>(qe) + ((P) + l15) * 32 + g * 2; \
    _Pragma("unroll")                                                          \
    for (int kc = 0; kc < 4; ++kc) {                                           \
      qv[kc * 2 + 0] = qb[kc * 8 + 0];                                         \
      qv[kc * 2 + 1] = qb[kc * 8 + 1];                                         \
    } }

  // ---- prologue: weights/consts, q(tile0) to regs, stage tiles 0,1 ----
  const bf16x8* wf = (const bf16x8*)wsf;
  bf16x8 wqf[4], wkf[2], wvf[2], wof[2][2];
  #pragma unroll
  for (int kc = 0; kc < 4; ++kc) wqf[kc] = wf[WQF(h, kc) + lane];
  #pragma unroll
  for (int kc = 0; kc < 2; ++kc) {
    wkf[kc] = wf[WKF(h, kc) + lane];
    wvf[kc] = wf[WVF(h, kc) + lane];
    wof[0][kc] = wf[WOF(2 * h + 0, kc) + lane];
    wof[1][kc] = wf[WOF(2 * h + 1, kc) + lane];
  }

  const float m0 = tmk_p[0], m1 = tmk_p[1], m2 = tmk_p[2], m3 = tmk_p[3];
  const float biasv[4] = {65504.0f * (m0 - 1.0f), 65504.0f * (m1 - 1.0f),
                          65504.0f * (m2 - 1.0f), 65504.0f * (m3 - 1.0f)};
  const float tmk = (m0 + m1 + m2 + m3 > 0.0f) ? 1.0f : 0.0f;

  f32x4 obf[2];
  {
    const f32x4* obase = reinterpret_cast<const f32x4*>(ob);
    #pragma unroll
    for (int j = 0; j < 2; ++j) {
      const f32x4 o = obase[(2 * h + j) * 4 + g];
      #pragma unroll
      for (int r = 0; r < 4; ++r) obf[j][r] = o[r] * tmk;
    }
  }

  f32x4 qv[8];
  LOADQ(blockIdx.x * 16)
  __builtin_amdgcn_sched_barrier(0);
  STAGE(inb0, blockIdx.x * 16)
  STAGE(inb1, (blockIdx.x + NBLK) * 16)
  __builtin_amdgcn_sched_barrier(0);

// Queue discipline (steady state), oldest -> newest at BODY(it)'s WAITVM:
//   [STAGE(it) 4] [qload(it+1) 8, STAGE(it+2) 4, store 2]  => WAITVM(14).
// First body: only STAGE(1) younger => WAITVM(4).
// qload precedes STAGE in-body so compiler's auto vmcnt for q-regs (6) never
// drains the in-flight DMA.
#define BODY(IT, CB, WN)                                                       \
{                                                                              \
  const int p0 = (blockIdx.x + (IT) * NBLK) * 16;                              \
  __builtin_amdgcn_sched_barrier(0);                                           \
  WAITVM(WN);                                                                  \
  __builtin_amdgcn_s_barrier();                                                \
  __builtin_amdgcn_sched_barrier(0);                                           \
  f32x4 qT = (f32x4){0.f, 0.f, 0.f, 0.f};                                      \
  _Pragma("unroll")                                                            \
  for (int kc = 0; kc < 4; ++kc) {                                             \
    bf16x8 aq;                                                                 \
    _Pragma("unroll")                                                          \
    for (int e = 0; e < 4; ++e) {                                              \
      aq[e]     = (short)bfc(qv[kc * 2 + 0][e]);                               \
      aq[e + 4] = (short)bfc(qv[kc * 2 + 1][e]);                               \
    }                                                                          \
    qT = __builtin_amdgcn_mfma_f32_16x16x32_bf16(wqf[kc], aq, qT, 0, 0, 0);    \
  }                                                                            \
  float ssum = 0.f;                                                            \
  f32x4 wvT = (f32x4){0.f, 0.f, 0.f, 0.f};                                     \
  _Pragma("unroll")                                                            \
  for (int t = 0; t < 4; ++t) {                                                \
    const char* trow = (CB) + t * 4096 + l15 * 256;                            \
    bf16x8 at0, at1;                                                           \
    { f32x4 lo = *(const f32x4*)(trow + ((g * 32) ^ swz));                     \
      f32x4 hi = *(const f32x4*)(trow + ((g * 32 + 16) ^ swz));                \
      _Pragma("unroll")                                                        \
      for (int e = 0; e < 4; ++e) { at0[e] = (short)bfc(lo[e]); at0[e + 4] = (short)bfc(hi[e]); } } \
    { f32x4 lo = *(const f32x4*)(trow + ((128 + g * 32) ^ swz));               \
      f32x4 hi = *(const f32x4*)(trow + ((128 + g * 32 + 16) ^ swz));          \
      _Pragma("unroll")                                                        \
      for (int e = 0; e < 4; ++e) { at1[e] = (short)bfc(lo[e]); at1[e + 4] = (short)bfc(hi[e]); } } \
    f32x4 kT = (f32x4){0.f, 0.f, 0.f, 0.f};                                    \
    f32x4 vT = (f32x4){0.f, 0.f, 0.f, 0.f};                                    \
    kT = __builtin_amdgcn_mfma_f32_16x16x32_bf16(wkf[0], at0, kT, 0, 0, 0);    \
    kT = __builtin_amdgcn_mfma_f32_16x16x32_bf16(wkf[1], at1, kT, 0, 0, 0);    \
    vT = __builtin_amdgcn_mfma_f32_16x16x32_bf16(wvf[0], at0, vT, 0, 0, 0);    \
    vT = __builtin_amdgcn_mfma_f32_16x16x32_bf16(wvf[1], at1, vT, 0, 0, 0);    \
    float lg = qT[0] * kT[0] + qT[1] * kT[1] + qT[2] * kT[2] + qT[3] * kT[3];  \
    lg += __shfl_xor(lg, 16);                                                  \
    lg += __shfl_xor(lg, 32);                                                  \
    const float w = __expf(lg + biasv[t]);                                     \
    ssum += w;                                                                 \
    _Pragma("unroll")                                                          \
    for (int r = 0; r < 4; ++r) wvT[r] += w * vT[r];                           \
  }                                                                            \
  { const float inv = tmk / fmaxf(ssum, 1e-30f);                               \
    u32 pk0 = (u32)bfc(wvT[0] * inv) | ((u32)bfc(wvT[1] * inv) << 16);         \
    u32 pk1 = (u32)bfc(wvT[2] * inv) | ((u32)bfc(wvT[3] * inv) << 16);         \
    const int hb = h * 32 + g * 8;                                             \
    *(u32*)(wvsh + ((l15 * 128 + hb) ^ swz))     = pk0;                        \
    *(u32*)(wvsh + ((l15 * 128 + hb + 4) ^ swz)) = pk1; }                      \
  __builtin_amdgcn_sched_barrier(0);                                           \
  asm volatile("s_waitcnt lgkmcnt(0)" ::: "memory");                           \
  __builtin_amdgcn_s_barrier();   /* CB fully read by all waves */             \
  __builtin_amdgcn_sched_barrier(0);                                           \
  { const int nqp = ((IT) + 1 < ITERS) ? (blockIdx.x + ((IT) + 1) * NBLK) * 16 : p0; \
    LOADQ(nqp) }                                                               \
  __builtin_amdgcn_sched_barrier(0);                                           \
  { const int sit = ((IT) + 2 < ITERS) ? (IT) + 2 : (IT);                      \
    STAGE(CB, (blockIdx.x + sit * NBLK) * 16) }                                \
  __builtin_amdgcn_sched_barrier(0);                                           \
  bf16x8 bwv0 = *(const bf16x8*)(wvsh + ((l15 * 128 + g * 16)      ^ swz));    \
  bf16x8 bwv1 = *(const bf16x8*)(wvsh + ((l15 * 128 + 64 + g * 16) ^ swz));    \
  _Pragma("unroll")                                                            \
  for (int j = 0; j < 2; ++j) {                                                \
    f32x4 acc = (f32x4){0.f, 0.f, 0.f, 0.f};                                   \
    acc = __builtin_amdgcn_mfma_f32_16x16x32_bf16(wof[j][0], bwv0, acc, 0, 0, 0); \
    acc = __builtin_amdgcn_mfma_f32_16x16x32_bf16(wof[j][1], bwv1, acc, 0, 0, 0); \
    f32x4 res;                                                                 \
    _Pragma("unroll")                                                          \
    for (int r = 0; r < 4; ++r) res[r] = acc[r] + obf[j][r];                   \
    *(f32x4*)(out + (size_t)(p0 + l15) * 128 + (2 * h + j) * 16 + g * 4) = res; \
  }                                                                            \
}

  BODY(0, inb0, 4)
  BODY(1, inb1, 14)
  for (int ith = 1; ith < ITERS / 2; ++ith) {
    BODY(2 * ith,     inb0, 14)
    BODY(2 * ith + 1, inb1, 14)
  }
}

extern "C" void kernel_launch(void* const* d_in, const int* in_sizes, int n_in,
                              void* d_out, int out_size, void* d_ws, size_t ws_size,
                              hipStream_t stream) {
  const float* qe  = (const float*)d_in[0];
  const float* tpr = (const float*)d_in[1];
  const float* tmk = (const float*)d_in[2];
  const float* wq  = (const float*)d_in[3];
  const float* wv_ = (const float*)d_in[5];
  const float* wk  = (const float*)d_in[4];
  const float* wo  = (const float*)d_in[6];
  const float* ob  = (const float*)d_in[7];
  float* out = (float*)d_out;
  u16* wsf = (u16*)d_ws;

  prep_kernel<<<96, 256, 0, stream>>>(wq, wk, wv_, wo, wsf);
  tpa_kernel<<<NBLK, 256, 0, stream>>>(qe, tpr, tmk, ob, wsf, out);
}